// Round 1
// baseline (210.115 us; speedup 1.0000x reference)
//
#include <hip/hip_runtime.h>

// Embedding: out[t, :] = W[:, x[t]] + b   (W [256,100000] row-major f32)
//
// Round 9: L3-rewarm + pipeline trims.
// Evidence: k2 at 58.8us = 169.5MB / 2.88 TB/s == prior session's COLD
// read+write ceiling (~3 TB/s). Same session measured L3-warm read+write =
// 4.6 TB/s. W (102.4MB) fits in the 256MB Infinity Cache; it is only cold
// because the ~800MB ws poison between iterations flushes L3. So: fuse a
// grid-stride streaming read of W into k1 (k1 is atomic-latency-bound and
// uses no BW) -> W is L3-resident when k2 runs -> k2 should drop to ~37-44us.
// Trims: flags[] (256KB write + 256KB read + 65K-thread k3) replaced by an
// overflow list + counter (always empty for this input); k1 goes to 1 token
// per thread on a 1024-block grid (shorter atomic dep chains, more TLP).

#define VOCAB 100000
#define EMBED 256
#define NTOK  (32 * 2048)
#define TILEW 16                  // vocab cols per bin = one 64B line
#define NTILE (VOCAB / TILEW)     // 6250 bins
#define CAP   64                  // slots per bin (Poisson mean 10.5; P(>64)~0)
#define LSTRIDE 260               // floats; 260*4=1040 (16B-aligned rows, b128-able)

#define K1_BLOCKS 1024

// workspace ints:
//   cnt   [0, NTILE)            zeroed by memset
//   ovf_cnt at [NTILE]          zeroed by same memset (contiguous)
//   list  [8192, 8192+NTILE*CAP)
//   ovf_list follows            (only first ovf_cnt entries ever read)
#define WS_CNT_OFF   0
#define WS_OVF_OFF   NTILE
#define WS_LIST_OFF  8192
#define WS_OVFL_OFF  (WS_LIST_OFF + NTILE * CAP)
#define WS_INTS      (WS_OVFL_OFF + NTOK)

__global__ __launch_bounds__(256) void k1_bucket_prefetch(
    const int* __restrict__ x,
    const float* __restrict__ W,
    int* __restrict__ cnt,
    int* __restrict__ ovf_cnt,
    int* __restrict__ list,
    int* __restrict__ ovf_list)
{
    const int tid = blockIdx.x * 256 + threadIdx.x;

    // --- token bucketing: one token per thread (single atomic round-trip) ---
    if (tid < NTOK) {
        const int v   = x[tid];
        const int bin = v >> 4;
        const int i   = v & 15;
        const int pos = atomicAdd(&cnt[bin], 1);
        if (pos < CAP) {
            list[bin * CAP + pos] = tid | (i << 16);
        } else {
            const int o = atomicAdd(ovf_cnt, 1);
            if (o < NTOK) ovf_list[o] = tid;   // never taken for this input
        }
    }

    // --- W prefetch: plain (cached) streaming read of all 102.4MB.
    // Memory-side Infinity Cache retains it for k2 (169.5MB total working
    // set < 256MB L3). Atomic latency above hides under this BW work.
    const float4* Wv = reinterpret_cast<const float4*>(W);
    const int nvec = EMBED * VOCAB / 4;     // 6,400,000 float4
    float acc = 0.f;
    #pragma unroll 4
    for (int k = tid; k < nvec; k += K1_BLOCKS * 256) {
        const float4 w = Wv[k];
        acc += w.x + w.y + w.z + w.w;
    }
    asm volatile("" :: "v"(acc));           // keep loads live, no store
}

__global__ __launch_bounds__(256) void k2_scatter(
    const float* __restrict__ W,
    const float* __restrict__ bias,
    const int* __restrict__ cnt,
    const int* __restrict__ list,
    float* __restrict__ out)
{
    __shared__ float tileT[TILEW * LSTRIDE];   // [i][e]
    __shared__ int   slist[CAP];

    const int bin = blockIdx.x;
    const int v0  = bin << 4;
    const int t   = threadIdx.x;

    if (t < CAP) slist[t] = list[bin * CAP + t];   // 256B contiguous prefetch

    // stage 16x256 tile transposed: 4 float4/thread, each 64B line read once.
    // staging-store banks: (4*(i4+k)+e)%32 with 4*i4%32 in {0,16} -> 2-way = free.
    #pragma unroll
    for (int j = 0; j < 4; ++j) {
        const int e  = j * 64 + (t >> 2);
        const int i4 = (t & 3) << 2;
        const float4 w = *reinterpret_cast<const float4*>(
            W + (size_t)e * VOCAB + v0 + i4);
        tileT[(i4 + 0) * LSTRIDE + e] = w.x;
        tileT[(i4 + 1) * LSTRIDE + e] = w.y;
        tileT[(i4 + 2) * LSTRIDE + e] = w.z;
        tileT[(i4 + 3) * LSTRIDE + e] = w.w;
    }
    __syncthreads();

    int n = cnt[bin];                // wave-uniform scalar load
    if (n > CAP) n = CAP;

    const int wave = t >> 6;
    const int lane = t & 63;
    const float4 bv = *reinterpret_cast<const float4*>(bias + lane * 4);

    for (int k = wave; k < n; k += 4) {
        const int packed = slist[k];
        const int tok = packed & 0xFFFF;
        const int i   = packed >> 16;
        // aligned 16B LDS read (row start i*1040, lane offset 16B) -> ds_read_b128
        const float4 s = *reinterpret_cast<const float4*>(
            &tileT[i * LSTRIDE + lane * 4]);
        float4 r;
        r.x = s.x + bv.x;  r.y = s.y + bv.y;
        r.z = s.z + bv.z;  r.w = s.w + bv.w;
        *reinterpret_cast<float4*>(out + (size_t)tok * EMBED + lane * 4) = r;
    }
}

__global__ __launch_bounds__(256) void k3_cleanup(
    const int* __restrict__ x,
    const float* __restrict__ W,
    const float* __restrict__ bias,
    const int* __restrict__ ovf_cnt,
    const int* __restrict__ ovf_list,
    float* __restrict__ out)
{
    __shared__ int n_sh;
    if (threadIdx.x == 0) {
        int n = *ovf_cnt;
        n_sh = (n > NTOK) ? NTOK : n;
    }
    __syncthreads();
    const int n = n_sh;                 // 0 for this input -> immediate exit
    const int e = threadIdx.x;          // 256 threads == EMBED
    for (int k = blockIdx.x; k < n; k += gridDim.x) {
        const int t = ovf_list[k];
        const int v = x[t];
        out[(size_t)t * EMBED + e] = W[(size_t)e * VOCAB + v] + bias[e];
    }
}

// fallback: direct column gather, if ws too small
__global__ __launch_bounds__(256) void embed_gather_direct(
    const int* __restrict__ x,
    const float* __restrict__ W,
    const float* __restrict__ bias,
    float* __restrict__ out)
{
    const int tid   = blockIdx.x * blockDim.x + threadIdx.x;
    const int token = tid >> 6;
    const int e     = (tid & 63) << 2;
    if (token >= NTOK) return;
    const int v = x[token];
    const float4 bv = *reinterpret_cast<const float4*>(bias + e);
    float4 r;
    r.x = W[(size_t)(e + 0) * VOCAB + v] + bv.x;
    r.y = W[(size_t)(e + 1) * VOCAB + v] + bv.y;
    r.z = W[(size_t)(e + 2) * VOCAB + v] + bv.z;
    r.w = W[(size_t)(e + 3) * VOCAB + v] + bv.w;
    *reinterpret_cast<float4*>(out + (size_t)token * EMBED + e) = r;
}

extern "C" void kernel_launch(void* const* d_in, const int* in_sizes, int n_in,
                              void* d_out, int out_size, void* d_ws, size_t ws_size,
                              hipStream_t stream)
{
    const int*   x = (const int*)d_in[0];
    const float* W = (const float*)d_in[1];
    const float* b = (const float*)d_in[2];
    float*     out = (float*)d_out;

    if (ws_size >= (size_t)WS_INTS * sizeof(int)) {
        int* ws       = (int*)d_ws;
        int* cnt      = ws + WS_CNT_OFF;
        int* ovf_cnt  = ws + WS_OVF_OFF;
        int* list     = ws + WS_LIST_OFF;
        int* ovf_list = ws + WS_OVFL_OFF;

        hipMemsetAsync(cnt, 0, (NTILE + 1) * sizeof(int), stream);  // cnt + ovf_cnt
        k1_bucket_prefetch<<<K1_BLOCKS, 256, 0, stream>>>(x, W, cnt, ovf_cnt,
                                                          list, ovf_list);
        k2_scatter<<<NTILE, 256, 0, stream>>>(W, b, cnt, list, out);
        k3_cleanup<<<32,    256, 0, stream>>>(x, W, b, ovf_cnt, ovf_list, out);
    } else {
        embed_gather_direct<<<NTOK * 64 / 256, 256, 0, stream>>>(x, W, b, out);
    }
}

// Round 2
// 190.361 us; speedup vs baseline: 1.1038x; 1.1038x over previous
//
#include <hip/hip_runtime.h>

// Embedding: out[t, :] = W[:, x[t]] + b   (W [256,100000] row-major f32)
//
// Round 10: revert R9's W-prefetch (falsified: +20us cost, no k2 payback —
// L3 residency does not lift the scattered-read rate). New mechanism:
// attack DRAM row-activation cost of the scattered read stream itself.
//   a) TILEW 16->32: each block reads 256 rows x 128B (two back-to-back
//      float4 per row) instead of 256 x 64B -> half the scattered-line
//      count, same total traffic (102.4MB). LDS 33.5KB -> 4 blocks/CU,
//      but 8 loads/thread keeps in-flight bytes/CU at 128KB (unchanged).
//   b) bijective XCD-chunked bin swizzle (m204): concurrently-resident
//      same-XCD blocks cover contiguous line spans per W row region
//      instead of round-robin spraying -> DRAM row-buffer + L2 locality.
// Kept from R9 (structural trims, independent of this mechanism):
// overflow-list instead of flags[] (kills 512KB of flag traffic + 65K-thread
// k3), memset covers cnt+ovf_cnt.

#define VOCAB 100000
#define EMBED 256
#define NTOK  (32 * 2048)
#define TILEW 32                  // vocab cols per bin = one 128B span per row
#define NTILE (VOCAB / TILEW)     // 3125 bins
#define CAP   64                  // slots per bin (Poisson mean 21.0; P(>64)~1e-14)
#define LSTRIDE 260               // floats; 260*4=1040 (16B-aligned rows, b128-able)

// workspace ints:
//   cnt   [0, NTILE)            zeroed by memset
//   ovf_cnt at [NTILE]          zeroed by same memset (contiguous)
//   list  [8192, 8192+NTILE*CAP)
//   ovf_list follows            (only first ovf_cnt entries ever read)
#define WS_CNT_OFF   0
#define WS_OVF_OFF   NTILE
#define WS_LIST_OFF  8192
#define WS_OVFL_OFF  (WS_LIST_OFF + NTILE * CAP)
#define WS_INTS      (WS_OVFL_OFF + NTOK)

__global__ __launch_bounds__(256) void k1_bucket(
    const int* __restrict__ x,
    int* __restrict__ cnt,
    int* __restrict__ ovf_cnt,
    int* __restrict__ list,
    int* __restrict__ ovf_list)
{
    int t4 = (blockIdx.x * 256 + threadIdx.x) * 4;
    if (t4 >= NTOK) return;
    const int4 v4 = *reinterpret_cast<const int4*>(x + t4);
    #pragma unroll
    for (int j = 0; j < 4; ++j) {
        const int v   = (&v4.x)[j];
        const int t   = t4 + j;
        const int bin = v >> 5;
        const int i   = v & 31;
        const int pos = atomicAdd(&cnt[bin], 1);
        if (pos < CAP) {
            list[bin * CAP + pos] = t | (i << 16);
        } else {
            const int o = atomicAdd(ovf_cnt, 1);
            if (o < NTOK) ovf_list[o] = t;   // never taken for this input
        }
    }
}

__global__ __launch_bounds__(256) void k2_scatter(
    const float* __restrict__ W,
    const float* __restrict__ bias,
    const int* __restrict__ cnt,
    const int* __restrict__ list,
    float* __restrict__ out)
{
    __shared__ float tileT[TILEW * LSTRIDE];   // [i][e], 33280B
    __shared__ int   slist[CAP];

    // bijective XCD-chunked swizzle (m204): XCD k processes a contiguous
    // chunk of bins -> concurrent same-XCD blocks read adjacent 128B spans.
    const int bid = blockIdx.x;
    const int x8  = bid & 7;
    const int idx = bid >> 3;
    const int q   = NTILE >> 3;          // 390
    const int r   = NTILE & 7;           // 5; x8<5 chunks get q+1 (=391) bins
    const int bin = (x8 < r ? x8 * (q + 1) : r * (q + 1) + (x8 - r) * q) + idx;

    const int v0  = bin << 5;
    const int t   = threadIdx.x;

    if (t < CAP) slist[t] = list[bin * CAP + t];   // 256B contiguous prefetch

    // stage 32x256 tile transposed: 8 float4/thread; per W row the two 64B
    // halves (h=0,1) issue back-to-back -> 128B contiguous per row.
    // staging-store banks: ((i4+k)*260 + e) % 32 = (4*i4 + e + 4k) % 32 with
    // 4*i4 % 32 in {0,16} -> 2 lanes/bank = free (m136).
    #pragma unroll
    for (int j = 0; j < 4; ++j) {
        const int e = j * 64 + (t >> 2);
        #pragma unroll
        for (int h = 0; h < 2; ++h) {
            const int i4 = ((t & 3) << 2) + (h << 4);
            const float4 w = *reinterpret_cast<const float4*>(
                W + (size_t)e * VOCAB + v0 + i4);
            tileT[(i4 + 0) * LSTRIDE + e] = w.x;
            tileT[(i4 + 1) * LSTRIDE + e] = w.y;
            tileT[(i4 + 2) * LSTRIDE + e] = w.z;
            tileT[(i4 + 3) * LSTRIDE + e] = w.w;
        }
    }
    __syncthreads();

    int n = cnt[bin];                // wave-uniform scalar load
    if (n > CAP) n = CAP;

    const int wave = t >> 6;
    const int lane = t & 63;
    const float4 bv = *reinterpret_cast<const float4*>(bias + lane * 4);

    for (int k = wave; k < n; k += 4) {
        const int packed = slist[k];
        const int tok = packed & 0xFFFF;
        const int i   = packed >> 16;
        // contiguous 1KB row read across the wave -> conflict-free b128
        const float4 s = *reinterpret_cast<const float4*>(
            &tileT[i * LSTRIDE + lane * 4]);
        float4 r4;
        r4.x = s.x + bv.x;  r4.y = s.y + bv.y;
        r4.z = s.z + bv.z;  r4.w = s.w + bv.w;
        *reinterpret_cast<float4*>(out + (size_t)tok * EMBED + lane * 4) = r4;
    }
}

__global__ __launch_bounds__(256) void k3_cleanup(
    const int* __restrict__ x,
    const float* __restrict__ W,
    const float* __restrict__ bias,
    const int* __restrict__ ovf_cnt,
    const int* __restrict__ ovf_list,
    float* __restrict__ out)
{
    __shared__ int n_sh;
    if (threadIdx.x == 0) {
        int n = *ovf_cnt;
        n_sh = (n > NTOK) ? NTOK : n;
    }
    __syncthreads();
    const int n = n_sh;                 // 0 for this input -> immediate exit
    const int e = threadIdx.x;          // 256 threads == EMBED
    for (int k = blockIdx.x; k < n; k += gridDim.x) {
        const int t = ovf_list[k];
        const int v = x[t];
        out[(size_t)t * EMBED + e] = W[(size_t)e * VOCAB + v] + bias[e];
    }
}

// fallback: direct column gather, if ws too small
__global__ __launch_bounds__(256) void embed_gather_direct(
    const int* __restrict__ x,
    const float* __restrict__ W,
    const float* __restrict__ bias,
    float* __restrict__ out)
{
    const int tid   = blockIdx.x * blockDim.x + threadIdx.x;
    const int token = tid >> 6;
    const int e     = (tid & 63) << 2;
    if (token >= NTOK) return;
    const int v = x[token];
    const float4 bv = *reinterpret_cast<const float4*>(bias + e);
    float4 r;
    r.x = W[(size_t)(e + 0) * VOCAB + v] + bv.x;
    r.y = W[(size_t)(e + 1) * VOCAB + v] + bv.y;
    r.z = W[(size_t)(e + 2) * VOCAB + v] + bv.z;
    r.w = W[(size_t)(e + 3) * VOCAB + v] + bv.w;
    *reinterpret_cast<float4*>(out + (size_t)token * EMBED + e) = r;
}

extern "C" void kernel_launch(void* const* d_in, const int* in_sizes, int n_in,
                              void* d_out, int out_size, void* d_ws, size_t ws_size,
                              hipStream_t stream)
{
    const int*   x = (const int*)d_in[0];
    const float* W = (const float*)d_in[1];
    const float* b = (const float*)d_in[2];
    float*     out = (float*)d_out;

    if (ws_size >= (size_t)WS_INTS * sizeof(int)) {
        int* ws       = (int*)d_ws;
        int* cnt      = ws + WS_CNT_OFF;
        int* ovf_cnt  = ws + WS_OVF_OFF;
        int* list     = ws + WS_LIST_OFF;
        int* ovf_list = ws + WS_OVFL_OFF;

        hipMemsetAsync(cnt, 0, (NTILE + 1) * sizeof(int), stream);  // cnt + ovf_cnt
        k1_bucket <<<NTOK / 4 / 256, 256, 0, stream>>>(x, cnt, ovf_cnt, list, ovf_list);
        k2_scatter<<<NTILE,          256, 0, stream>>>(W, b, cnt, list, out);
        k3_cleanup<<<32,             256, 0, stream>>>(x, W, b, ovf_cnt, ovf_list, out);
    } else {
        embed_gather_direct<<<NTOK * 64 / 256, 256, 0, stream>>>(x, W, b, out);
    }
}

// Round 4
// 190.253 us; speedup vs baseline: 1.1044x; 1.0006x over previous
//
#include <hip/hip_runtime.h>

// Embedding: out[t, :] = W[:, x[t]] + b   (W [256,100000] row-major f32)
//
// Round 12 = Round 11 resubmitted verbatim (R3 was an infra failure: the
// MI355X container died twice before the kernel ever ran; theory untested).
//
// Round 11: break the staging load->ds_write dependency chain.
// Evidence: k2 pinned at 58.8-59.0us across R0-R2 while FETCH_SIZE halved
// (51.6MB, half of W served from L3), granule doubled, swizzle added ->
// not HBM/DRAM/L3-bound. VALUBusy 2.7%, VGPR=52: compiler emits
// load->waitcnt->ds_write x4 per float4 (no regs to hold more) -> ONE
// global load in flight per wave. 1024B/wave-load / ~91ns observed ->
// exactly the measured 2.9 TB/s. Latency x concurrency=1 is the limiter.
// Fix: two-phase staging. Phase L: issue all 8 float4 loads into registers
// (independent, 8 in flight). Compiler memory barrier. Phase S: 32 LDS
// stores. Per-CU outstanding bytes go 4KB -> 128KB; expect the read stream
// to ride to the ~3.1 TB/s read ceiling (m13) -> k2 ~35-45us.
// Everything else identical to R10 (TILEW=32, XCD-chunked bins, overflow
// list, LSTRIDE=260 b128 scatter reads).

#define VOCAB 100000
#define EMBED 256
#define NTOK  (32 * 2048)
#define TILEW 32                  // vocab cols per bin = one 128B span per row
#define NTILE (VOCAB / TILEW)     // 3125 bins
#define CAP   64                  // slots per bin (Poisson mean 21.0; P(>64)~1e-14)
#define LSTRIDE 260               // floats; 260*4=1040 (16B-aligned rows, b128-able)

// workspace ints:
//   cnt   [0, NTILE)            zeroed by memset
//   ovf_cnt at [NTILE]          zeroed by same memset (contiguous)
//   list  [8192, 8192+NTILE*CAP)
//   ovf_list follows            (only first ovf_cnt entries ever read)
#define WS_CNT_OFF   0
#define WS_OVF_OFF   NTILE
#define WS_LIST_OFF  8192
#define WS_OVFL_OFF  (WS_LIST_OFF + NTILE * CAP)
#define WS_INTS      (WS_OVFL_OFF + NTOK)

__global__ __launch_bounds__(256) void k1_bucket(
    const int* __restrict__ x,
    int* __restrict__ cnt,
    int* __restrict__ ovf_cnt,
    int* __restrict__ list,
    int* __restrict__ ovf_list)
{
    int t4 = (blockIdx.x * 256 + threadIdx.x) * 4;
    if (t4 >= NTOK) return;
    const int4 v4 = *reinterpret_cast<const int4*>(x + t4);
    #pragma unroll
    for (int j = 0; j < 4; ++j) {
        const int v   = (&v4.x)[j];
        const int t   = t4 + j;
        const int bin = v >> 5;
        const int i   = v & 31;
        const int pos = atomicAdd(&cnt[bin], 1);
        if (pos < CAP) {
            list[bin * CAP + pos] = t | (i << 16);
        } else {
            const int o = atomicAdd(ovf_cnt, 1);
            if (o < NTOK) ovf_list[o] = t;   // never taken for this input
        }
    }
}

__global__ __launch_bounds__(256) void k2_scatter(
    const float* __restrict__ W,
    const float* __restrict__ bias,
    const int* __restrict__ cnt,
    const int* __restrict__ list,
    float* __restrict__ out)
{
    __shared__ float tileT[TILEW * LSTRIDE];   // [i][e], 33280B
    __shared__ int   slist[CAP];

    // bijective XCD-chunked swizzle (m204): XCD k processes a contiguous
    // chunk of bins -> concurrent same-XCD blocks read adjacent 128B spans.
    const int bid = blockIdx.x;
    const int x8  = bid & 7;
    const int idx = bid >> 3;
    const int q   = NTILE >> 3;          // 390
    const int r   = NTILE & 7;           // 5; x8<5 chunks get q+1 (=391) bins
    const int bin = (x8 < r ? x8 * (q + 1) : r * (q + 1) + (x8 - r) * q) + idx;

    const int v0  = bin << 5;
    const int t   = threadIdx.x;

    // ---- Phase L: issue ALL 8 independent global loads first ----
    float4 wreg[8];
    #pragma unroll
    for (int j = 0; j < 4; ++j) {
        const int e = j * 64 + (t >> 2);
        #pragma unroll
        for (int h = 0; h < 2; ++h) {
            const int i4 = ((t & 3) << 2) + (h << 4);
            wreg[j * 2 + h] = *reinterpret_cast<const float4*>(
                W + (size_t)e * VOCAB + v0 + i4);
        }
    }
    if (t < CAP) slist[t] = list[bin * CAP + t];   // 256B contiguous prefetch

    // compiler barrier: no ds_write may be hoisted between the loads above
    asm volatile("" ::: "memory");

    // ---- Phase S: 32 LDS stores (transposed tile) ----
    // staging-store banks: ((i4+k)*260 + e) % 32 = (16*(t&3)+(t>>2)+4k) % 32
    // -> 2 lanes/bank = free (m136).
    #pragma unroll
    for (int j = 0; j < 4; ++j) {
        const int e = j * 64 + (t >> 2);
        #pragma unroll
        for (int h = 0; h < 2; ++h) {
            const int i4 = ((t & 3) << 2) + (h << 4);
            const float4 w = wreg[j * 2 + h];
            tileT[(i4 + 0) * LSTRIDE + e] = w.x;
            tileT[(i4 + 1) * LSTRIDE + e] = w.y;
            tileT[(i4 + 2) * LSTRIDE + e] = w.z;
            tileT[(i4 + 3) * LSTRIDE + e] = w.w;
        }
    }
    __syncthreads();

    int n = cnt[bin];                // wave-uniform scalar load
    if (n > CAP) n = CAP;

    const int wave = t >> 6;
    const int lane = t & 63;
    const float4 bv = *reinterpret_cast<const float4*>(bias + lane * 4);

    for (int k = wave; k < n; k += 4) {
        const int packed = slist[k];
        const int tok = packed & 0xFFFF;
        const int i   = packed >> 16;
        // contiguous 1KB row read across the wave -> conflict-free b128
        const float4 s = *reinterpret_cast<const float4*>(
            &tileT[i * LSTRIDE + lane * 4]);
        float4 r4;
        r4.x = s.x + bv.x;  r4.y = s.y + bv.y;
        r4.z = s.z + bv.z;  r4.w = s.w + bv.w;
        *reinterpret_cast<float4*>(out + (size_t)tok * EMBED + lane * 4) = r4;
    }
}

__global__ __launch_bounds__(256) void k3_cleanup(
    const int* __restrict__ x,
    const float* __restrict__ W,
    const float* __restrict__ bias,
    const int* __restrict__ ovf_cnt,
    const int* __restrict__ ovf_list,
    float* __restrict__ out)
{
    __shared__ int n_sh;
    if (threadIdx.x == 0) {
        int n = *ovf_cnt;
        n_sh = (n > NTOK) ? NTOK : n;
    }
    __syncthreads();
    const int n = n_sh;                 // 0 for this input -> immediate exit
    const int e = threadIdx.x;          // 256 threads == EMBED
    for (int k = blockIdx.x; k < n; k += gridDim.x) {
        const int t = ovf_list[k];
        const int v = x[t];
        out[(size_t)t * EMBED + e] = W[(size_t)e * VOCAB + v] + bias[e];
    }
}

// fallback: direct column gather, if ws too small
__global__ __launch_bounds__(256) void embed_gather_direct(
    const int* __restrict__ x,
    const float* __restrict__ W,
    const float* __restrict__ bias,
    float* __restrict__ out)
{
    const int tid   = blockIdx.x * blockDim.x + threadIdx.x;
    const int token = tid >> 6;
    const int e     = (tid & 63) << 2;
    if (token >= NTOK) return;
    const int v = x[token];
    const float4 bv = *reinterpret_cast<const float4*>(bias + e);
    float4 r;
    r.x = W[(size_t)(e + 0) * VOCAB + v] + bv.x;
    r.y = W[(size_t)(e + 1) * VOCAB + v] + bv.y;
    r.z = W[(size_t)(e + 2) * VOCAB + v] + bv.z;
    r.w = W[(size_t)(e + 3) * VOCAB + v] + bv.w;
    *reinterpret_cast<float4*>(out + (size_t)token * EMBED + e) = r;
}

extern "C" void kernel_launch(void* const* d_in, const int* in_sizes, int n_in,
                              void* d_out, int out_size, void* d_ws, size_t ws_size,
                              hipStream_t stream)
{
    const int*   x = (const int*)d_in[0];
    const float* W = (const float*)d_in[1];
    const float* b = (const float*)d_in[2];
    float*     out = (float*)d_out;

    if (ws_size >= (size_t)WS_INTS * sizeof(int)) {
        int* ws       = (int*)d_ws;
        int* cnt      = ws + WS_CNT_OFF;
        int* ovf_cnt  = ws + WS_OVF_OFF;
        int* list     = ws + WS_LIST_OFF;
        int* ovf_list = ws + WS_OVFL_OFF;

        hipMemsetAsync(cnt, 0, (NTILE + 1) * sizeof(int), stream);  // cnt + ovf_cnt
        k1_bucket <<<NTOK / 4 / 256, 256, 0, stream>>>(x, cnt, ovf_cnt, list, ovf_list);
        k2_scatter<<<NTILE,          256, 0, stream>>>(W, b, cnt, list, out);
        k3_cleanup<<<32,             256, 0, stream>>>(x, W, b, ovf_cnt, ovf_list, out);
    } else {
        embed_gather_direct<<<NTOK * 64 / 256, 256, 0, stream>>>(x, W, b, out);
    }
}